// Round 5
// baseline (1810.641 us; speedup 1.0000x reference)
//
#include <hip/hip_runtime.h>
#include <hip/hip_bf16.h>
#include <math.h>

#define N_NODES 50000
#define N_EDGES 800000
#define IN_CH   256
#define EDGE_DIM 32
#define NH 4
#define NC 32
#define HC 128   // NH*NC

// Dual-dtype scalar load: f32 flag selects fp32 vs bf16 interpretation of the raw buffer.
__device__ __forceinline__ float ldf(const void* p, long i, bool f32) {
    return f32 ? ((const float*)p)[i]
               : __bfloat162float(((const __hip_bfloat16*)p)[i]);
}

// Dual-width index loads: idx64 => buffer is int64 [2,E] (values < 2^31, read low words).
__device__ __forceinline__ int ld_src(const int* ei, long e, bool idx64) {
    return idx64 ? ei[2 * e] : ei[e];
}
__device__ __forceinline__ int ld_dst(const int* ei, long e, bool idx64) {
    return idx64 ? ei[2 * ((long)N_EDGES + e)] : ei[(long)N_EDGES + e];
}

// ---------------- dtype detection (runs every call, deterministic) ----------------
// Float storage: sample even-position uint16 words of x.
//   true bf16 buffer:            words = bf16 Gaussian values -> nonzero, exp != 0xFF
//   fp32 buffer, bf16-rounded:   words = zeroed low mantissa  -> all zero
//   fp32 buffer, full precision: words = random low mantissa  -> ~1/256 have exp pattern 0xFF
// => fp32 iff (zeros > half) or (any 0xFF-exponent pattern).
// Index width: int64 [2,E] with values < 2^31 has all odd 32-bit words zero.
__global__ __launch_bounds__(256) void detect_k(const unsigned short* __restrict__ xu,
                                                const int* __restrict__ ei,
                                                int* __restrict__ flag) {
    __shared__ int zc, bc, nz_idx;
    if (threadIdx.x == 0) { zc = 0; bc = 0; nz_idx = 0; }
    __syncthreads();
    int z = 0, b = 0, hi = 0;
    for (int i = threadIdx.x; i < 16384; i += 256) {
        const unsigned short w = xu[2 * i];
        if (w == 0) ++z;
        if ((w & 0x7F80) == 0x7F80) ++b;
    }
    for (int i = threadIdx.x; i < 8192; i += 256)
        if (ei[2 * i + 1] != 0) hi = 1;
    atomicAdd(&zc, z);
    atomicAdd(&bc, b);
    if (hi) atomicAdd(&nz_idx, 1);
    __syncthreads();
    if (threadIdx.x == 0) {
        flag[0] = (zc > 8192 || bc > 0) ? 1 : 0;  // 1 => fp32 float buffers
        flag[1] = (nz_idx == 0) ? 1 : 0;          // 1 => int64 indices
    }
}

// ---------------- init: s = 0, acc = 0 ----------------
__global__ __launch_bounds__(256) void init_ws_k(float* __restrict__ s_ws,
                                                 float* __restrict__ acc_ws) {
    long i = (long)blockIdx.x * 256 + threadIdx.x;
    if (i < (long)N_NODES * NH) s_ws[i] = 0.0f;
    if (i < (long)N_NODES * HC) acc_ws[i] = 0.0f;
}

// ---------------- node GEMMs: x_src = x@W_src, x_dst = x@W_dst ----------------
__global__ __launch_bounds__(256) void node_gemm_k(const void* __restrict__ x,
                                                   const void* __restrict__ Wsrc,
                                                   const void* __restrict__ Wdst,
                                                   const int* __restrict__ flag,
                                                   float* __restrict__ xsrc,
                                                   float* __restrict__ xdst) {
    const bool f32 = (flag[0] != 0);
    __shared__ float sx[8][IN_CH];
    const int tid = threadIdx.x;
    const long n0 = (long)blockIdx.x * 8;
    #pragma unroll
    for (int r = 0; r < 8; ++r)
        sx[r][tid] = ldf(x, (n0 + r) * IN_CH + tid, f32);
    __syncthreads();

    const int mat = tid >> 7;
    const int col = tid & 127;
    const void* __restrict__ W = mat ? Wdst : Wsrc;
    float acc[8] = {0,0,0,0,0,0,0,0};
    for (int k = 0; k < IN_CH; k += 4) {
        const float w0 = ldf(W, (long)(k + 0) * HC + col, f32);
        const float w1 = ldf(W, (long)(k + 1) * HC + col, f32);
        const float w2 = ldf(W, (long)(k + 2) * HC + col, f32);
        const float w3 = ldf(W, (long)(k + 3) * HC + col, f32);
        #pragma unroll
        for (int r = 0; r < 8; ++r) {
            const float4 sv = *(const float4*)&sx[r][k];
            acc[r] += sv.x * w0 + sv.y * w1 + sv.z * w2 + sv.w * w3;
        }
    }
    float* __restrict__ o = mat ? xdst : xsrc;
    #pragma unroll
    for (int r = 0; r < 8; ++r)
        o[(n0 + r) * HC + col] = acc[r];
}

// ---------------- fused edge pass ----------------
// e_feat on the fly; alpha_raw; decay; ea = exp(alpha) (no max-shift: it cancels
// exactly in the normalization and |alpha| <= ~3, so fp32 exp cannot overflow);
// atomicAdd into s[dst,h] and acc[dst,128].
__global__ __launch_bounds__(256) void edge_fused_k(const int* __restrict__ ei,
                                                    const void* __restrict__ eattr,
                                                    const void* __restrict__ dw,
                                                    const void* __restrict__ Wedge,
                                                    const void* __restrict__ att,
                                                    const void* __restrict__ sscale,
                                                    const int* __restrict__ flag,
                                                    const float* __restrict__ xsrc,
                                                    const float* __restrict__ xdst,
                                                    float* __restrict__ ea_ws,
                                                    float* __restrict__ s_ws,
                                                    float* __restrict__ acc_ws,
                                                    float* __restrict__ araw_out) {
    const bool f32   = (flag[0] != 0);
    const bool idx64 = (flag[1] != 0);
    __shared__ float sW[EDGE_DIM * HC];      // 16 KiB W_edge
    __shared__ float sea[8][EDGE_DIM];
    __shared__ float s_raw[8][NH];
    __shared__ float s_ea[8][NH];
    __shared__ int   s_dst[8];

    const int tid = threadIdx.x;
    for (int i = tid; i < EDGE_DIM * HC; i += 256)
        sW[i] = ldf(Wedge, i, f32);

    const int le = tid >> 5;       // local edge 0..7
    const int t  = tid & 31;       // lane within edge
    const long e = (long)blockIdx.x * 8 + le;

    sea[le][t] = ldf(eattr, e * EDGE_DIM + t, f32);
    const int src = ld_src(ei, e, idx64);
    const int dst = ld_dst(ei, e, idx64);
    if (t == 0) s_dst[le] = dst;

    float att4[4];
    #pragma unroll
    for (int i = 0; i < 4; ++i) att4[i] = ldf(att, t * 4 + i, f32);
    __syncthreads();

    // e_feat for the 4 owned channels (flat channel j = t*4 + i, head = t>>3)
    float ef0 = 0, ef1 = 0, ef2 = 0, ef3 = 0;
    const float4* sW4 = (const float4*)sW;
    #pragma unroll 8
    for (int k = 0; k < EDGE_DIM; ++k) {
        const float a = sea[le][k];           // LDS broadcast
        const float4 w = sW4[k * 32 + t];
        ef0 += a * w.x; ef1 += a * w.y; ef2 += a * w.z; ef3 += a * w.w;
    }

    const float4 xs = *(const float4*)(xsrc + (long)src * HC + t * 4);
    const float4 xd = *(const float4*)(xdst + (long)dst * HC + t * 4);

    float p = tanhf(xs.x + xd.x + ef0) * att4[0]
            + tanhf(xs.y + xd.y + ef1) * att4[1]
            + tanhf(xs.z + xd.z + ef2) * att4[2]
            + tanhf(xs.w + xd.w + ef3) * att4[3];

    // reduce 8 lanes -> one alpha per head
    p += __shfl_down(p, 4, 8);
    p += __shfl_down(p, 2, 8);
    p += __shfl_down(p, 1, 8);

    if ((t & 7) == 0) {
        const int h = t >> 3;
        s_raw[le][h] = p;
        const float d = powf(ldf(dw, e, f32), ldf(sscale, h, f32));
        s_ea[le][h] = expf(p * d);
    }
    __syncthreads();

    // weighted message accumulation (all 32 lanes; 4 channels each)
    const float eo = s_ea[le][t >> 3];
    float* base = acc_ws + (long)dst * HC + t * 4;
    atomicAdd(base + 0, eo * xs.x);
    atomicAdd(base + 1, eo * xs.y);
    atomicAdd(base + 2, eo * xs.z);
    atomicAdd(base + 3, eo * xs.w);

    if (tid < 32) {                // coalesced per-edge/head writeback
        const int le2 = tid >> 2, h2 = tid & 3;
        const long e2 = (long)blockIdx.x * 8 + le2;
        araw_out[e2 * 4 + h2] = s_raw[le2][h2];
        const float v = s_ea[le2][h2];
        ea_ws[e2 * 4 + h2] = v;
        atomicAdd(&s_ws[(long)s_dst[le2] * 4 + h2], v);
    }
}

// ---------------- node finalize: out = acc / (s + 1e-8) ----------------
__global__ __launch_bounds__(256) void node_final_k(const float* __restrict__ acc_ws,
                                                    const float* __restrict__ s_ws,
                                                    float* __restrict__ out) {
    const long i = (long)blockIdx.x * 256 + threadIdx.x;
    if (i >= (long)N_NODES * HC) return;
    const long n = i >> 7;
    const int h = (int)((i & 127) >> 5);
    out[i] = acc_ws[i] / (s_ws[n * 4 + h] + 1e-8f);
}

// ---------------- edge finalize: alpha_norm = ea / (s[dst] + 1e-8) ----------------
__global__ __launch_bounds__(256) void edge_norm_k(const int* __restrict__ ei,
                                                   const int* __restrict__ flag,
                                                   const float* __restrict__ ea_ws,
                                                   const float* __restrict__ s_ws,
                                                   float* __restrict__ anorm) {
    const bool idx64 = (flag[1] != 0);
    const long i = (long)blockIdx.x * 256 + threadIdx.x;
    if (i >= (long)N_EDGES * NH) return;
    const long e = i >> 2;
    const int h = (int)(i & 3);
    const int dst = ld_dst(ei, e, idx64);
    anorm[i] = ea_ws[i] / (s_ws[(long)dst * 4 + h] + 1e-8f);
}

extern "C" void kernel_launch(void* const* d_in, const int* in_sizes, int n_in,
                              void* d_out, int out_size, void* d_ws, size_t ws_size,
                              hipStream_t stream) {
    const void* x      = d_in[0];
    const int*  ei     = (const int*)d_in[1];
    const void* eattr  = d_in[2];
    const void* dw     = d_in[3];
    const void* Wsrc   = d_in[4];
    const void* Wdst   = d_in[5];
    const void* Wedge  = d_in[6];
    const void* att    = d_in[7];
    const void* sscale = d_in[8];

    float* out   = (float*)d_out;                   // reference output dtype: float32
    float* anorm = out + (long)N_NODES * HC;
    float* araw  = anorm + (long)N_EDGES * NH;

    float* ws    = (float*)d_ws;
    int*   flag  = (int*)d_ws;                      // 64-float pad
    float* xsrc  = ws + 64;                         // N*128
    float* xdst  = xsrc + (long)N_NODES * HC;       // N*128
    float* ea    = xdst + (long)N_NODES * HC;       // E*4
    float* s_ws  = ea + (long)N_EDGES * NH;         // N*4
    float* acc   = s_ws + (long)N_NODES * NH;       // N*128

    detect_k<<<1, 256, 0, stream>>>((const unsigned short*)x, ei, flag);
    init_ws_k<<<(N_NODES * HC + 255) / 256, 256, 0, stream>>>(s_ws, acc);
    node_gemm_k<<<N_NODES / 8, 256, 0, stream>>>(x, Wsrc, Wdst, flag, xsrc, xdst);
    edge_fused_k<<<N_EDGES / 8, 256, 0, stream>>>(ei, eattr, dw, Wedge, att, sscale,
                                                  flag, xsrc, xdst, ea, s_ws, acc, araw);
    node_final_k<<<(N_NODES * HC + 255) / 256, 256, 0, stream>>>(acc, s_ws, out);
    edge_norm_k<<<(N_EDGES * NH + 255) / 256, 256, 0, stream>>>(ei, flag, ea, s_ws, anorm);
}

// Round 6
// 1166.189 us; speedup vs baseline: 1.5526x; 1.5526x over previous
//
#include <hip/hip_runtime.h>
#include <hip/hip_bf16.h>
#include <math.h>

#define N_NODES 50000
#define N_EDGES 800000
#define IN_CH   256
#define EDGE_DIM 32
#define NH 4
#define NC 32
#define HC 128   // NH*NC
#define SCAN_N 50176   // 196 * 256 >= N_NODES

// Dual-dtype scalar load: f32 flag selects fp32 vs bf16 interpretation of the raw buffer.
__device__ __forceinline__ float ldf(const void* p, long i, bool f32) {
    return f32 ? ((const float*)p)[i]
               : __bfloat162float(((const __hip_bfloat16*)p)[i]);
}

// Dual-width index loads: idx64 => buffer is int64 [2,E] (values < 2^31, read low words).
__device__ __forceinline__ int ld_src(const int* ei, long e, bool idx64) {
    return idx64 ? ei[2 * e] : ei[e];
}
__device__ __forceinline__ int ld_dst(const int* ei, long e, bool idx64) {
    return idx64 ? ei[2 * ((long)N_EDGES + e)] : ei[(long)N_EDGES + e];
}

// ---------------- dtype detection (runs every call, deterministic) ----------------
__global__ __launch_bounds__(256) void detect_k(const unsigned short* __restrict__ xu,
                                                const int* __restrict__ ei,
                                                int* __restrict__ flag) {
    __shared__ int zc, bc, nz_idx;
    if (threadIdx.x == 0) { zc = 0; bc = 0; nz_idx = 0; }
    __syncthreads();
    int z = 0, b = 0, hi = 0;
    for (int i = threadIdx.x; i < 16384; i += 256) {
        const unsigned short w = xu[2 * i];
        if (w == 0) ++z;
        if ((w & 0x7F80) == 0x7F80) ++b;
    }
    for (int i = threadIdx.x; i < 8192; i += 256)
        if (ei[2 * i + 1] != 0) hi = 1;
    atomicAdd(&zc, z);
    atomicAdd(&bc, b);
    if (hi) atomicAdd(&nz_idx, 1);
    __syncthreads();
    if (threadIdx.x == 0) {
        flag[0] = (zc > 8192 || bc > 0) ? 1 : 0;  // 1 => fp32 float buffers
        flag[1] = (nz_idx == 0) ? 1 : 0;          // 1 => int64 indices
    }
}

// ---------------- CSR build ----------------
__global__ __launch_bounds__(256) void zero_deg_k(int* __restrict__ deg) {
    const int i = blockIdx.x * 256 + threadIdx.x;
    if (i < N_NODES) deg[i] = 0;
}

__global__ __launch_bounds__(256) void hist_k(const int* __restrict__ ei,
                                              const int* __restrict__ flag,
                                              int* __restrict__ deg) {
    const bool idx64 = (flag[1] != 0);
    const long e = (long)blockIdx.x * 256 + threadIdx.x;
    if (e < N_EDGES) atomicAdd(&deg[ld_dst(ei, e, idx64)], 1);
}

// single-block exclusive scan: deg[0..N) -> row_ptr[0..N], cursor copy
__global__ __launch_bounds__(256) void scan_k(const int* __restrict__ deg,
                                              int* __restrict__ row_ptr,
                                              int* __restrict__ cursor) {
    __shared__ int wsum[4];
    __shared__ int s_carry;
    const int tid = threadIdx.x;
    const int lane = tid & 63, wid = tid >> 6;
    if (tid == 0) s_carry = 0;
    __syncthreads();
    for (int base = 0; base < SCAN_N; base += 256) {
        const int i = base + tid;
        const int v = (i < N_NODES) ? deg[i] : 0;
        int x = v;
        #pragma unroll
        for (int off = 1; off < 64; off <<= 1) {
            const int t = __shfl_up(x, off);
            if (lane >= off) x += t;
        }
        if (lane == 63) wsum[wid] = x;
        __syncthreads();
        int wpre = 0;
        for (int w = 0; w < wid; ++w) wpre += wsum[w];
        const int total = wsum[0] + wsum[1] + wsum[2] + wsum[3];
        const int excl = s_carry + wpre + x - v;
        if (i < N_NODES) { row_ptr[i] = excl; cursor[i] = excl; }
        __syncthreads();
        if (tid == 0) s_carry += total;
        __syncthreads();
    }
    if (tid == 0) row_ptr[N_NODES] = s_carry;
}

__global__ __launch_bounds__(256) void scatter_k(const int* __restrict__ ei,
                                                 const int* __restrict__ flag,
                                                 int* __restrict__ cursor,
                                                 int* __restrict__ eids,
                                                 int* __restrict__ esrc) {
    const bool idx64 = (flag[1] != 0);
    const long e = (long)blockIdx.x * 256 + threadIdx.x;
    if (e >= N_EDGES) return;
    const int dst = ld_dst(ei, e, idx64);
    const int src = ld_src(ei, e, idx64);
    const int pos = atomicAdd(&cursor[dst], 1);
    eids[pos] = (int)e;
    esrc[pos] = src;
}

// ---------------- node GEMMs: x_src = x@W_src, x_dst = x@W_dst ----------------
__global__ __launch_bounds__(256) void node_gemm_k(const void* __restrict__ x,
                                                   const void* __restrict__ Wsrc,
                                                   const void* __restrict__ Wdst,
                                                   const int* __restrict__ flag,
                                                   float* __restrict__ xsrc,
                                                   float* __restrict__ xdst) {
    const bool f32 = (flag[0] != 0);
    __shared__ float sx[8][IN_CH];
    const int tid = threadIdx.x;
    const long n0 = (long)blockIdx.x * 8;
    #pragma unroll
    for (int r = 0; r < 8; ++r)
        sx[r][tid] = ldf(x, (n0 + r) * IN_CH + tid, f32);
    __syncthreads();

    const int mat = tid >> 7;
    const int col = tid & 127;
    const void* __restrict__ W = mat ? Wdst : Wsrc;
    float acc[8] = {0,0,0,0,0,0,0,0};
    for (int k = 0; k < IN_CH; k += 4) {
        const float w0 = ldf(W, (long)(k + 0) * HC + col, f32);
        const float w1 = ldf(W, (long)(k + 1) * HC + col, f32);
        const float w2 = ldf(W, (long)(k + 2) * HC + col, f32);
        const float w3 = ldf(W, (long)(k + 3) * HC + col, f32);
        #pragma unroll
        for (int r = 0; r < 8; ++r) {
            const float4 sv = *(const float4*)&sx[r][k];
            acc[r] += sv.x * w0 + sv.y * w1 + sv.z * w2 + sv.w * w3;
        }
    }
    float* __restrict__ o = mat ? xdst : xsrc;
    #pragma unroll
    for (int r = 0; r < 8; ++r)
        o[(n0 + r) * HC + col] = acc[r];
}

// ---------------- edge alpha pass (no atomics) ----------------
__global__ __launch_bounds__(256) void edge_alpha_k(const int* __restrict__ ei,
                                                    const void* __restrict__ eattr,
                                                    const void* __restrict__ dw,
                                                    const void* __restrict__ Wedge,
                                                    const void* __restrict__ att,
                                                    const void* __restrict__ sscale,
                                                    const int* __restrict__ flag,
                                                    const float* __restrict__ xsrc,
                                                    const float* __restrict__ xdst,
                                                    float* __restrict__ ea_ws,
                                                    float* __restrict__ araw_out) {
    const bool f32   = (flag[0] != 0);
    const bool idx64 = (flag[1] != 0);
    __shared__ float sW[EDGE_DIM * HC];      // 16 KiB W_edge
    __shared__ float sea[8][EDGE_DIM];
    __shared__ float s_raw[8][NH];
    __shared__ float s_ea[8][NH];

    const int tid = threadIdx.x;
    for (int i = tid; i < EDGE_DIM * HC; i += 256)
        sW[i] = ldf(Wedge, i, f32);

    const int le = tid >> 5;       // local edge 0..7
    const int t  = tid & 31;       // lane within edge
    const long e = (long)blockIdx.x * 8 + le;

    sea[le][t] = ldf(eattr, e * EDGE_DIM + t, f32);
    const int src = ld_src(ei, e, idx64);
    const int dst = ld_dst(ei, e, idx64);

    float att4[4];
    #pragma unroll
    for (int i = 0; i < 4; ++i) att4[i] = ldf(att, t * 4 + i, f32);
    __syncthreads();

    // e_feat for the 4 owned channels (flat channel j = t*4 + i, head = t>>3)
    float ef0 = 0, ef1 = 0, ef2 = 0, ef3 = 0;
    const float4* sW4 = (const float4*)sW;
    #pragma unroll 8
    for (int k = 0; k < EDGE_DIM; ++k) {
        const float a = sea[le][k];           // LDS broadcast
        const float4 w = sW4[k * 32 + t];
        ef0 += a * w.x; ef1 += a * w.y; ef2 += a * w.z; ef3 += a * w.w;
    }

    const float4 xs = *(const float4*)(xsrc + (long)src * HC + t * 4);
    const float4 xd = *(const float4*)(xdst + (long)dst * HC + t * 4);

    float p = tanhf(xs.x + xd.x + ef0) * att4[0]
            + tanhf(xs.y + xd.y + ef1) * att4[1]
            + tanhf(xs.z + xd.z + ef2) * att4[2]
            + tanhf(xs.w + xd.w + ef3) * att4[3];

    // reduce 8 lanes -> one alpha per head
    p += __shfl_down(p, 4, 8);
    p += __shfl_down(p, 2, 8);
    p += __shfl_down(p, 1, 8);

    if ((t & 7) == 0) {
        const int h = t >> 3;
        s_raw[le][h] = p;
        const float d = powf(ldf(dw, e, f32), ldf(sscale, h, f32));
        s_ea[le][h] = expf(p * d);
    }
    __syncthreads();

    if (tid < 32) {                // coalesced per-edge/head writeback
        const int le2 = tid >> 2, h2 = tid & 3;
        const long e2 = (long)blockIdx.x * 8 + le2;
        araw_out[e2 * 4 + h2] = s_raw[le2][h2];
        ea_ws[e2 * 4 + h2] = s_ea[le2][h2];
    }
}

// ---------------- CSR aggregation: one wave per dst node, no atomics ----------------
// lane owns channels {2*lane, 2*lane+1}; head h = lane>>4.
__global__ __launch_bounds__(256) void aggregate_k(const int* __restrict__ row_ptr,
                                                   const int* __restrict__ eids,
                                                   const int* __restrict__ esrc,
                                                   const float* __restrict__ ea_ws,
                                                   const float* __restrict__ xsrc,
                                                   float* __restrict__ s_ws,
                                                   float* __restrict__ out) {
    const int tid = threadIdx.x;
    const int lane = tid & 63;
    const int n = blockIdx.x * 4 + (tid >> 6);
    if (n >= N_NODES) return;
    const int h = lane >> 4;

    const int p0 = row_ptr[n];
    const int p1 = row_ptr[n + 1];

    float ax = 0.0f, ay = 0.0f, sa = 0.0f;
    for (int p = p0; p < p1; ++p) {
        const int e = eids[p];
        const int src = esrc[p];
        const float w = ea_ws[(long)e * 4 + h];
        const float2 xv = *(const float2*)(xsrc + (long)src * HC + (lane << 1));
        ax += w * xv.x;
        ay += w * xv.y;
        sa += w;
    }
    const float inv = 1.0f / (sa + 1e-8f);
    float* o = out + (long)n * HC + (lane << 1);
    o[0] = ax * inv;
    o[1] = ay * inv;
    if ((lane & 15) == 0) s_ws[(long)n * 4 + h] = sa;
}

// ---------------- edge finalize: alpha_norm = ea / (s[dst] + 1e-8) ----------------
__global__ __launch_bounds__(256) void edge_norm_k(const int* __restrict__ ei,
                                                   const int* __restrict__ flag,
                                                   const float* __restrict__ ea_ws,
                                                   const float* __restrict__ s_ws,
                                                   float* __restrict__ anorm) {
    const bool idx64 = (flag[1] != 0);
    const long i = (long)blockIdx.x * 256 + threadIdx.x;
    if (i >= (long)N_EDGES * NH) return;
    const long e = i >> 2;
    const int h = (int)(i & 3);
    const int dst = ld_dst(ei, e, idx64);
    anorm[i] = ea_ws[i] / (s_ws[(long)dst * 4 + h] + 1e-8f);
}

extern "C" void kernel_launch(void* const* d_in, const int* in_sizes, int n_in,
                              void* d_out, int out_size, void* d_ws, size_t ws_size,
                              hipStream_t stream) {
    const void* x      = d_in[0];
    const int*  ei     = (const int*)d_in[1];
    const void* eattr  = d_in[2];
    const void* dw     = d_in[3];
    const void* Wsrc   = d_in[4];
    const void* Wdst   = d_in[5];
    const void* Wedge  = d_in[6];
    const void* att    = d_in[7];
    const void* sscale = d_in[8];

    float* out   = (float*)d_out;                   // reference output dtype: float32
    float* anorm = out + (long)N_NODES * HC;
    float* araw  = anorm + (long)N_EDGES * NH;

    float* ws      = (float*)d_ws;
    int*   flag    = (int*)d_ws;                    // 64-float pad
    float* xsrc    = ws + 64;                       // N*128
    float* xdst    = xsrc + (long)N_NODES * HC;     // N*128
    float* ea      = xdst + (long)N_NODES * HC;     // E*4
    float* s_ws    = ea + (long)N_EDGES * NH;       // N*4
    int*   deg     = (int*)(s_ws + (long)N_NODES * NH);   // N
    int*   row_ptr = deg + N_NODES;                 // N+1
    int*   cursor  = row_ptr + N_NODES + 1;         // N
    int*   eids    = cursor + N_NODES;              // E
    int*   esrc    = eids + N_EDGES;                // E

    detect_k<<<1, 256, 0, stream>>>((const unsigned short*)x, ei, flag);
    zero_deg_k<<<(N_NODES + 255) / 256, 256, 0, stream>>>(deg);
    hist_k<<<(N_EDGES + 255) / 256, 256, 0, stream>>>(ei, flag, deg);
    scan_k<<<1, 256, 0, stream>>>(deg, row_ptr, cursor);
    scatter_k<<<(N_EDGES + 255) / 256, 256, 0, stream>>>(ei, flag, cursor, eids, esrc);
    node_gemm_k<<<N_NODES / 8, 256, 0, stream>>>(x, Wsrc, Wdst, flag, xsrc, xdst);
    edge_alpha_k<<<N_EDGES / 8, 256, 0, stream>>>(ei, eattr, dw, Wedge, att, sscale,
                                                  flag, xsrc, xdst, ea, araw);
    aggregate_k<<<(N_NODES + 3) / 4, 256, 0, stream>>>(row_ptr, eids, esrc, ea, xsrc, s_ws, out);
    edge_norm_k<<<((long)N_EDGES * NH + 255) / 256, 256, 0, stream>>>(ei, flag, ea, s_ws, anorm);
}